// Round 16
// baseline (101.837 us; speedup 1.0000x reference)
//
#include <hip/hip_runtime.h>

#define HID 64
#define IN_C 16

typedef __attribute__((ext_vector_type(8))) short short8;
typedef __attribute__((ext_vector_type(4))) float f32x4;

__device__ __forceinline__ float bitsf(unsigned u) { return __uint_as_float(u); }
__device__ __forceinline__ unsigned rne16(float f) {
    unsigned u = __float_as_uint(f);
    return (u + 0x7fffu + ((u >> 16) & 1u)) >> 16;
}
__device__ __forceinline__ float lanebcf(float v, int l) {
    return __int_as_float(__builtin_amdgcn_readlane(__float_as_int(v), l));
}
__device__ __forceinline__ float f4c(const float4& a, int c) {
    switch (c & 3) { case 0: return a.x; case 1: return a.y; case 2: return a.z; default: return a.w; }
}

// ---- k_init: pack stacked weights [WZ | W1+WQ | W1] into MFMA frags ----
__global__ void k_init(const float* __restrict__ M0, const float* __restrict__ W1,
                       const float* __restrict__ bM0, const float* __restrict__ b1,
                       ushort* __restrict__ WPhi, ushort* __restrict__ WPlo,
                       float* __restrict__ bias192) {
    int tid = blockIdx.x * 256 + threadIdx.x;
    if (tid >= 64 * 192) return;
    int cc = tid % 192;
    int k  = tid / 192;
    float w;
    if (cc < 64) {
        float a = 0.f;
#pragma unroll
        for (int m = 0; m < HID; ++m) a = fmaf(M0[k * HID + m], W1[m * HID + cc], a);
        w = a;
    } else if (cc < 128) {
        int c = cc - 64;
        float a = W1[k * HID + c];
#pragma unroll
        for (int m = 0; m < HID; ++m) a = fmaf(M0[(HID + k) * HID + m], W1[m * HID + c], a);
        w = a;
    } else {
        w = W1[k * HID + (cc - 128)];
    }
    unsigned wb = __float_as_uint(w);
    ushort hi = (ushort)(wb >> 16);
    float hif = __uint_as_float(wb & 0xffff0000u);
    ushort lo = (ushort)(__float_as_uint(w - hif) >> 16);
    int ct = cc >> 4, s = k >> 5, l = ((k >> 3) & 3) * 16 + (cc & 15), j = k & 7;
    int fi = ((ct * 2 + s) * 64 + l) * 8 + j;
    WPhi[fi] = hi;
    WPlo[fi] = lo;
    if (k == 0) {
        float bv;
        if (cc < 64) bv = 0.f;
        else if (cc < 128) {
            int c = cc - 64;
            float a = b1[c];
#pragma unroll
            for (int m = 0; m < HID; ++m) a = fmaf(bM0[m], W1[m * HID + c], a);
            bv = a;
        } else bv = b1[cc - 128];
        bias192[cc] = bv;
    }
}

// ---- fused: blocks [0,NB1) = LDS radix pass-1 histogram ; rest = MFMA precompute ----
// Transposed MFMA (A=W, B=h): lane holds 4 consecutive CHANNELS of one node -> vector stores.
__global__ __launch_bounds__(256) void k_pre_hist(
    const float* __restrict__ x, const float* __restrict__ W0, const float* __restrict__ b0,
    const ushort* __restrict__ WPhi, const ushort* __restrict__ WPlo,
    const float* __restrict__ bias192,
    ushort* __restrict__ zb, float* __restrict__ PQ, ushort* __restrict__ Ppb, int N,
    const int* __restrict__ ei, int* __restrict__ bhT, int E, int B1, int NB1)
{
    __shared__ ushort hhi[64 * 64];
    __shared__ ushort hlo[64 * 64];

    if ((int)blockIdx.x < NB1) {
        int* h = reinterpret_cast<int*>(hhi);   // reuse LDS (>=4KB)
        for (int i = threadIdx.x; i < B1; i += 256) h[i] = 0;
        __syncthreads();
        int CH = (E + NB1 - 1) / NB1;
        int e0 = blockIdx.x * CH;
        int e1 = min(e0 + CH, E);
        for (int e = e0 + (int)threadIdx.x; e < e1; e += 256)
            atomicAdd(&h[ei[E + e] >> 8], 1);
        __syncthreads();
        for (int i = threadIdx.x; i < B1; i += 256)
            bhT[(size_t)i * NB1 + blockIdx.x] = h[i];
        return;
    }

    int tid  = threadIdx.x;
    int lane = tid & 63;
    int w    = tid >> 6;
    int n0   = (blockIdx.x - NB1) * 64;

    float w0c[IN_C];
#pragma unroll
    for (int k = 0; k < IN_C; ++k) w0c[k] = W0[k * HID + lane];
    float b0l = b0[lane];

    short8 Whi[3][2], Wlo[3][2];
    float4 bias4[3];
#pragma unroll
    for (int i = 0; i < 3; ++i) {
        int ct = w * 3 + i;
#pragma unroll
        for (int s = 0; s < 2; ++s) {
            int fi = ((ct * 2 + s) * 64 + lane) * 8;
            Whi[i][s] = *reinterpret_cast<const short8*>(WPhi + fi);
            Wlo[i][s] = *reinterpret_cast<const short8*>(WPlo + fi);
        }
        bias4[i] = *reinterpret_cast<const float4*>(bias192 + ct * 16 + (lane >> 4) * 4);
    }

    int nx = n0 + w * 16 + (lane >> 2);
    float4 xq = make_float4(0.f, 0.f, 0.f, 0.f);
    if (nx < N) xq = *reinterpret_cast<const float4*>(x + (size_t)nx * IN_C + (lane & 3) * 4);

    // phase 1: wave-parallel x -> h (16 nodes/wave), split bf16, swizzled LDS
#pragma unroll
    for (int nn = 0; nn < 16; ++nn) {
        float acc = b0l;
#pragma unroll
        for (int k = 0; k < IN_C; ++k)
            acc = fmaf(lanebcf(f4c(xq, k & 3), 4 * nn + (k >> 2)), w0c[k], acc);
        float h = fmaxf(acc, 0.f);
        unsigned hb = __float_as_uint(h);
        ushort hi = (ushort)(hb >> 16);
        float hif = __uint_as_float(hb & 0xffff0000u);
        ushort lo = (ushort)(__float_as_uint(h - hif) >> 16);
        int nl = w * 16 + nn;
        int u  = ((lane >> 3) ^ (nl & 7));
        int off = nl * 64 + u * 8 + (lane & 7);
        hhi[off] = hi;
        hlo[off] = lo;
    }
    __syncthreads();

    // phase 2: transposed MFMA -> vectorized stores
#pragma unroll
    for (int st = 0; st < 4; ++st) {
        int nloc = st * 16 + (lane & 15);
        short8 Ahi[2], Alo[2];
#pragma unroll
        for (int s = 0; s < 2; ++s) {
            int u = (s * 4 + (lane >> 4)) ^ (nloc & 7);
            int off = nloc * 64 + u * 8;
            Ahi[s] = *reinterpret_cast<const short8*>(hhi + off);
            Alo[s] = *reinterpret_cast<const short8*>(hlo + off);
        }
        int n = n0 + st * 16 + (lane & 15);
#pragma unroll
        for (int i = 0; i < 3; ++i) {
            int ct = w * 3 + i;
            f32x4 acc = {bias4[i].x, bias4[i].y, bias4[i].z, bias4[i].w};
#pragma unroll
            for (int s = 0; s < 2; ++s) {
                acc = __builtin_amdgcn_mfma_f32_16x16x32_bf16(Whi[i][s], Ahi[s], acc, 0, 0, 0);
                acc = __builtin_amdgcn_mfma_f32_16x16x32_bf16(Whi[i][s], Alo[s], acc, 0, 0, 0);
                acc = __builtin_amdgcn_mfma_f32_16x16x32_bf16(Wlo[i][s], Ahi[s], acc, 0, 0, 0);
                acc = __builtin_amdgcn_mfma_f32_16x16x32_bf16(Wlo[i][s], Alo[s], acc, 0, 0, 0);
            }
            if (n < N) {
                int chb = ct * 16 + (lane >> 4) * 4;
                if (chb < 64) {
                    uint2 pk;
                    pk.x = rne16(acc[0]) | (rne16(acc[1]) << 16);
                    pk.y = rne16(acc[2]) | (rne16(acc[3]) << 16);
                    *reinterpret_cast<uint2*>(zb + (size_t)n * HID + chb) = pk;
                } else if (chb < 128) {
                    float4 v = make_float4(acc[0], acc[1], acc[2], acc[3]);
                    *reinterpret_cast<float4*>(PQ + (size_t)n * HID + (chb - 64)) = v;
                } else {
                    uint2 pk;
                    pk.x = rne16(acc[0]) | (rne16(acc[1]) << 16);
                    pk.y = rne16(acc[2]) | (rne16(acc[3]) << 16);
                    *reinterpret_cast<uint2*>(Ppb + (size_t)n * HID + (chb - 128)) = pk;
                }
            }
        }
    }
}

// ---- exclusive scan (16/thread, 4096/block): raw chunk scans + chunk totals ----
__global__ void k_scan1(const int* __restrict__ cnt, int* __restrict__ rs,
                        int* __restrict__ bsum, int M) {
    __shared__ int lds[256];
    int t = threadIdx.x;
    int base = blockIdx.x * 4096 + t * 16;
    int v[16];
    if (base + 16 <= M) {
#pragma unroll
        for (int u = 0; u < 4; ++u) {
            int4 w = *reinterpret_cast<const int4*>(cnt + base + u * 4);
            v[u * 4 + 0] = w.x; v[u * 4 + 1] = w.y; v[u * 4 + 2] = w.z; v[u * 4 + 3] = w.w;
        }
    } else {
#pragma unroll
        for (int u = 0; u < 16; ++u) v[u] = (base + u < M) ? cnt[base + u] : 0;
    }
    int run = 0;
#pragma unroll
    for (int u = 0; u < 16; ++u) { int tv = v[u]; v[u] = run; run += tv; }
    lds[t] = run;
    __syncthreads();
#pragma unroll
    for (int off = 1; off < 256; off <<= 1) {
        int xw = (t >= off) ? lds[t - off] : 0;
        __syncthreads();
        lds[t] += xw;
        __syncthreads();
    }
    int excl = lds[t] - run;
    if (t == 255) bsum[blockIdx.x] = lds[255];
#pragma unroll
    for (int u = 0; u < 16; ++u)
        if (base + u < M) rs[base + u] = excl + v[u];
}

// ---- radix pass 1b: scatter packed (src | (dst&255)<<24) via LDS cursors ----
// Fused bsum-exscan: cursors = off_raw[i*NB1+bid] + exscan(bsum)[(i*NB1+bid)>>12]
__global__ __launch_bounds__(256) void k_p1scat(const int* __restrict__ ei, const int* __restrict__ off,
                                                const int* __restrict__ bsum, int NBs,
                                                unsigned* __restrict__ tmp, int E, int B1) {
    __shared__ int cur[1024];
    __shared__ int lds[256];
    __shared__ int excl[256];
    int NB1 = gridDim.x;
    int t = threadIdx.x;
    int v = (t < NBs) ? bsum[t] : 0;
    lds[t] = v;
    __syncthreads();
#pragma unroll
    for (int o = 1; o < 256; o <<= 1) {
        int xw = (t >= o) ? lds[t - o] : 0;
        __syncthreads();
        lds[t] += xw;
        __syncthreads();
    }
    excl[t] = lds[t] - v;
    __syncthreads();
    for (int i = t; i < B1; i += 256) {
        int idx = i * NB1 + blockIdx.x;
        cur[i] = off[idx] + excl[idx >> 12];
    }
    __syncthreads();
    int CH = (E + NB1 - 1) / NB1;
    int e0 = blockIdx.x * CH;
    int e1 = min(e0 + CH, E);
    for (int e = e0 + t; e < e1; e += 256) {
        int s = ei[e];
        int d = ei[E + e];
        int pos = atomicAdd(&cur[d >> 8], 1);
        tmp[pos] = (unsigned)s | ((unsigned)(d & 255) << 24);
    }
}

// ---- radix pass 2: per-bucket 256-bin LDS counting sort -> flat CSR + row starts ----
__global__ __launch_bounds__(256) void k_p2(const unsigned* __restrict__ tmp, const int* __restrict__ off,
                                            const int* __restrict__ bsum, int NBs,
                                            int* __restrict__ rs, int* __restrict__ csr,
                                            int E, int N, int B1, int NB1) {
    __shared__ int h2[256];
    __shared__ int sc[256];
    __shared__ int cur[256];
    __shared__ int bb[2];
    int b = blockIdx.x;
    int t = threadIdx.x;

    {   // bsum exscan (reuse sc as scratch) -> bucket bounds
        int v = (t < NBs) ? bsum[t] : 0;
        sc[t] = v;
        __syncthreads();
#pragma unroll
        for (int o = 1; o < 256; o <<= 1) {
            int xw = (t >= o) ? sc[t - o] : 0;
            __syncthreads();
            sc[t] += xw;
            __syncthreads();
        }
        if (t == 0) {
            int i0 = b * NB1;
            bb[0] = off[i0] + (sc[i0 >> 12] - ((i0 >> 12) < NBs ? bsum[i0 >> 12] : 0));
        } else if (t == 1 && b < B1 - 1) {
            int i1 = (b + 1) * NB1;
            bb[1] = off[i1] + (sc[i1 >> 12] - ((i1 >> 12) < NBs ? bsum[i1 >> 12] : 0));
        } else if (t == 1) {
            bb[1] = E;
        }
    }
    __syncthreads();
    int bb0 = bb[0];
    int bb1 = bb[1];

    h2[t] = 0;
    __syncthreads();
    for (int i = bb0 + t; i < bb1; i += 256)
        atomicAdd(&h2[tmp[i] >> 24], 1);
    __syncthreads();

    int v = h2[t];
    sc[t] = v;
    __syncthreads();
#pragma unroll
    for (int o = 1; o < 256; o <<= 1) {
        int xw = (t >= o) ? sc[t - o] : 0;
        __syncthreads();
        sc[t] += xw;
        __syncthreads();
    }
    int excl = sc[t] - v;

    int node = b * 256 + t;
    if (node < N) rs[node] = bb0 + excl;
    if (b == B1 - 1 && t == 0) rs[N] = E;
    cur[t] = bb0 + excl;
    __syncthreads();

    for (int i = bb0 + t; i < bb1; i += 256) {
        unsigned ed = tmp[i];
        int pos = atomicAdd(&cur[ed >> 24], 1);
        csr[pos] = (int)(ed & 0x00FFFFFFu);
    }
}

// ---- bf16 gather (flat CSR, 2 edges/round per 16-lane group) + elementwise epilogue ----
__global__ __launch_bounds__(256) void k_final(
    const ushort* __restrict__ zb, const float* __restrict__ PQ, const ushort* __restrict__ Ppb,
    const int* __restrict__ rs, const int* __restrict__ csr,
    const float* __restrict__ W2, const float* __restrict__ b2,
    float* __restrict__ out, int N)
{
    int lane = threadIdx.x & 63;
    int g    = lane >> 4;
    int ql   = lane & 15;
    int oct  = ql & 7;
    int half = ql >> 3;
    int wid  = (blockIdx.x * 256 + threadIdx.x) >> 6;
    int nw   = (gridDim.x * 256) >> 6;

    int c0 = oct * 8 + half * 4;
    float4 w2v = *reinterpret_cast<const float4*>(W2 + c0);
    float b2s = b2[0];

    for (int n0 = wid * 4; n0 < N; n0 += nw * 4) {
        int ng   = n0 + g;
        bool okg = ng < N;

        int rv = okg ? rs[ng + half] : 0;
        int beg = __shfl(rv, g * 16 + 0);
        int end = __shfl(rv, g * 16 + 8);
        int deg = end - beg;
        int md = deg;
        md = max(md, __shfl_xor(md, 16));
        md = max(md, __shfl_xor(md, 32));

        float acc[8];
#pragma unroll
        for (int i = 0; i < 8; ++i) acc[i] = 0.f;

        for (int c = 0; c < md; c += 32) {
            int j0 = c + ql, j1 = c + 16 + ql;
            int ia = (j0 < deg) ? csr[beg + j0] : -1;
            int ib = (j1 < deg) ? csr[beg + j1] : -1;
#pragma unroll
            for (int tb = 0; tb < 4; ++tb) {
                if (tb > 0 && md <= c + 8 * tb) break;
                int srcs[4];
#pragma unroll
                for (int t4 = 0; t4 < 4; ++t4) {
                    int t = tb * 4 + t4;
                    int e = 2 * t + half;
                    srcs[t4] = __shfl(tb < 2 ? ia : ib, g * 16 + (e & 15));
                }
                uint4 rw[4];
#pragma unroll
                for (int t4 = 0; t4 < 4; ++t4) {
                    int s = srcs[t4] < 0 ? 0 : srcs[t4];
                    rw[t4] = *reinterpret_cast<const uint4*>(zb + (size_t)s * HID + oct * 8);
                }
#pragma unroll
                for (int t4 = 0; t4 < 4; ++t4) {
                    if (srcs[t4] >= 0) {
                        uint4 wv = rw[t4];
                        acc[0] += bitsf(wv.x << 16); acc[1] += bitsf(wv.x & 0xffff0000u);
                        acc[2] += bitsf(wv.y << 16); acc[3] += bitsf(wv.y & 0xffff0000u);
                        acc[4] += bitsf(wv.z << 16); acc[5] += bitsf(wv.z & 0xffff0000u);
                        acc[6] += bitsf(wv.w << 16); acc[7] += bitsf(wv.w & 0xffff0000u);
                    }
                }
            }
        }
#pragma unroll
        for (int i = 0; i < 8; ++i) acc[i] += __shfl_xor(acc[i], 8);

        float s0 = half ? acc[4] : acc[0];
        float s1 = half ? acc[5] : acc[1];
        float s2 = half ? acc[6] : acc[2];
        float s3 = half ? acc[7] : acc[3];

        float4 base = make_float4(0.f, 0.f, 0.f, 0.f);
        if (okg) {
            base = *reinterpret_cast<const float4*>(PQ + (size_t)ng * HID + c0);
            if (deg == 0) {
                uint2 pb = *reinterpret_cast<const uint2*>(Ppb + (size_t)ng * HID + c0);
                base.x = bitsf(pb.x << 16); base.y = bitsf(pb.x & 0xffff0000u);
                base.z = bitsf(pb.y << 16); base.w = bitsf(pb.y & 0xffff0000u);
            }
        }
        float rcpd = (deg > 0) ? (1.f / (float)deg) : 0.f;
        float y0 = base.x + s0 * rcpd;
        float y1 = base.y + s1 * rcpd;
        float y2 = base.z + s2 * rcpd;
        float y3 = base.w + s3 * rcpd;

        float part = fmaxf(y0, 0.f) * w2v.x + fmaxf(y1, 0.f) * w2v.y +
                     fmaxf(y2, 0.f) * w2v.z + fmaxf(y3, 0.f) * w2v.w;
#pragma unroll
        for (int off = 1; off < 16; off <<= 1) part += __shfl_xor(part, off);
        if (ql == 0 && okg) out[ng] = part + b2s;
    }
}

extern "C" void kernel_launch(void* const* d_in, const int* in_sizes, int n_in,
                              void* d_out, int out_size, void* d_ws, size_t ws_size,
                              hipStream_t stream) {
    const float* x   = (const float*)d_in[0];
    const int*   ei  = (const int*)d_in[1];
    const float* W0  = (const float*)d_in[2];
    const float* b0  = (const float*)d_in[3];
    const float* W1  = (const float*)d_in[4];
    const float* b1  = (const float*)d_in[5];
    const float* W2  = (const float*)d_in[6];
    const float* b2  = (const float*)d_in[7];
    const float* M0  = (const float*)d_in[8];
    const float* bM0 = (const float*)d_in[9];

    int N = in_sizes[0] / IN_C;
    int E = in_sizes[1] / 2;
    int B1 = (N + 255) >> 8;            // buckets of 256 nodes (<=1024 for N<=262144)
    int NB1 = 256;                      // pass-1 blocks
    int M2 = B1 * NB1;
    int NBs = (M2 + 4095) / 4096;       // scan chunks (<=256)

    ushort*   zb     = (ushort*)d_ws;                   // N*64 bf16
    float*    PQ     = (float*)(zb + (size_t)N * HID);  // N*64 f32
    ushort*   Ppb    = (ushort*)(PQ + (size_t)N * HID); // N*64 bf16
    ushort*   WPhi   = Ppb + (size_t)N * HID;           // 12288
    ushort*   WPlo   = WPhi + 12288;                    // 12288
    float*    bias192= (float*)(WPlo + 12288);          // 192
    int*      bhT    = (int*)(bias192 + 192);           // M2
    int*      off    = bhT + (size_t)M2;                // M2
    int*      bsum   = off + (size_t)M2;                // 256
    int*      rs     = bsum + 256;                      // N+1
    unsigned* tmp    = (unsigned*)(rs + N + 1);         // E (packed)
    int*      csr    = (int*)(tmp + (size_t)E);         // E
    float*    out    = (float*)d_out;

    int npre = (N + 63) / 64;

    k_init<<<48, 256, 0, stream>>>(M0, W1, bM0, b1, WPhi, WPlo, bias192);
    k_pre_hist<<<NB1 + npre, 256, 0, stream>>>(x, W0, b0, WPhi, WPlo, bias192,
                                               zb, PQ, Ppb, N, ei, bhT, E, B1, NB1);
    k_scan1<<<NBs, 256, 0, stream>>>(bhT, off, bsum, M2);
    k_p1scat<<<NB1, 256, 0, stream>>>(ei, off, bsum, NBs, tmp, E, B1);
    k_p2<<<B1, 256, 0, stream>>>(tmp, off, bsum, NBs, rs, csr, E, N, B1, NB1);
    k_final<<<2048, 256, 0, stream>>>(zb, PQ, Ppb, rs, csr, W2, b2, out, N);
}

// Round 17
// 94.530 us; speedup vs baseline: 1.0773x; 1.0773x over previous
//
#include <hip/hip_runtime.h>

#define HID 64
#define IN_C 16
#define BKT 64      // nodes per bucket (pass-2)
#define LCAP 2048   // LDS csr capacity (mean 1024 + 32 sigma)

typedef __attribute__((ext_vector_type(8))) short short8;
typedef __attribute__((ext_vector_type(4))) float f32x4;

__device__ __forceinline__ float bitsf(unsigned u) { return __uint_as_float(u); }
__device__ __forceinline__ unsigned rne16(float f) {
    unsigned u = __float_as_uint(f);
    return (u + 0x7fffu + ((u >> 16) & 1u)) >> 16;
}
__device__ __forceinline__ float lanebcf(float v, int l) {
    return __int_as_float(__builtin_amdgcn_readlane(__float_as_int(v), l));
}
__device__ __forceinline__ float f4c(const float4& a, int c) {
    switch (c & 3) { case 0: return a.x; case 1: return a.y; case 2: return a.z; default: return a.w; }
}

// ---- k_init: pack stacked weights [WZ | W1+WQ | W1] into MFMA frags ----
__global__ void k_init(const float* __restrict__ M0, const float* __restrict__ W1,
                       const float* __restrict__ bM0, const float* __restrict__ b1,
                       ushort* __restrict__ WPhi, ushort* __restrict__ WPlo,
                       float* __restrict__ bias192) {
    int tid = blockIdx.x * 256 + threadIdx.x;
    if (tid >= 64 * 192) return;
    int cc = tid % 192;
    int k  = tid / 192;
    float w;
    if (cc < 64) {
        float a = 0.f;
#pragma unroll
        for (int m = 0; m < HID; ++m) a = fmaf(M0[k * HID + m], W1[m * HID + cc], a);
        w = a;
    } else if (cc < 128) {
        int c = cc - 64;
        float a = W1[k * HID + c];
#pragma unroll
        for (int m = 0; m < HID; ++m) a = fmaf(M0[(HID + k) * HID + m], W1[m * HID + c], a);
        w = a;
    } else {
        w = W1[k * HID + (cc - 128)];
    }
    unsigned wb = __float_as_uint(w);
    ushort hi = (ushort)(wb >> 16);
    float hif = __uint_as_float(wb & 0xffff0000u);
    ushort lo = (ushort)(__float_as_uint(w - hif) >> 16);
    int ct = cc >> 4, s = k >> 5, l = ((k >> 3) & 3) * 16 + (cc & 15), j = k & 7;
    int fi = ((ct * 2 + s) * 64 + l) * 8 + j;
    WPhi[fi] = hi;
    WPlo[fi] = lo;
    if (k == 0) {
        float bv;
        if (cc < 64) bv = 0.f;
        else if (cc < 128) {
            int c = cc - 64;
            float a = b1[c];
#pragma unroll
            for (int m = 0; m < HID; ++m) a = fmaf(bM0[m], W1[m * HID + c], a);
            bv = a;
        } else bv = b1[cc - 128];
        bias192[cc] = bv;
    }
}

// ---- fused: blocks [0,NB1) = LDS radix pass-1 histogram (dst>>6) ; rest = MFMA precompute ----
__global__ __launch_bounds__(256) void k_pre_hist(
    const float* __restrict__ x, const float* __restrict__ W0, const float* __restrict__ b0,
    const ushort* __restrict__ WPhi, const ushort* __restrict__ WPlo,
    const float* __restrict__ bias192,
    ushort* __restrict__ zb, float* __restrict__ PQ, ushort* __restrict__ Ppb, int N,
    const int* __restrict__ ei, int* __restrict__ bhT, int E, int B1, int NB1)
{
    __shared__ ushort hhi[64 * 64];
    __shared__ ushort hlo[64 * 64];

    if ((int)blockIdx.x < NB1) {
        int* h = reinterpret_cast<int*>(hhi);   // 2048 ints >= B1
        for (int i = threadIdx.x; i < B1; i += 256) h[i] = 0;
        __syncthreads();
        int CH = (E + NB1 - 1) / NB1;
        int e0 = blockIdx.x * CH;
        int e1 = min(e0 + CH, E);
        for (int e = e0 + (int)threadIdx.x; e < e1; e += 256)
            atomicAdd(&h[ei[E + e] >> 6], 1);
        __syncthreads();
        for (int i = threadIdx.x; i < B1; i += 256)
            bhT[(size_t)i * NB1 + blockIdx.x] = h[i];
        return;
    }

    int tid  = threadIdx.x;
    int lane = tid & 63;
    int w    = tid >> 6;
    int n0   = (blockIdx.x - NB1) * 64;

    float w0c[IN_C];
#pragma unroll
    for (int k = 0; k < IN_C; ++k) w0c[k] = W0[k * HID + lane];
    float b0l = b0[lane];

    short8 Whi[3][2], Wlo[3][2];
    float4 bias4[3];
#pragma unroll
    for (int i = 0; i < 3; ++i) {
        int ct = w * 3 + i;
#pragma unroll
        for (int s = 0; s < 2; ++s) {
            int fi = ((ct * 2 + s) * 64 + lane) * 8;
            Whi[i][s] = *reinterpret_cast<const short8*>(WPhi + fi);
            Wlo[i][s] = *reinterpret_cast<const short8*>(WPlo + fi);
        }
        bias4[i] = *reinterpret_cast<const float4*>(bias192 + ct * 16 + (lane >> 4) * 4);
    }

    int nx = n0 + w * 16 + (lane >> 2);
    float4 xq = make_float4(0.f, 0.f, 0.f, 0.f);
    if (nx < N) xq = *reinterpret_cast<const float4*>(x + (size_t)nx * IN_C + (lane & 3) * 4);

    // phase 1: wave-parallel x -> h (16 nodes/wave), split bf16, swizzled LDS
#pragma unroll
    for (int nn = 0; nn < 16; ++nn) {
        float acc = b0l;
#pragma unroll
        for (int k = 0; k < IN_C; ++k)
            acc = fmaf(lanebcf(f4c(xq, k & 3), 4 * nn + (k >> 2)), w0c[k], acc);
        float h = fmaxf(acc, 0.f);
        unsigned hb = __float_as_uint(h);
        ushort hi = (ushort)(hb >> 16);
        float hif = __uint_as_float(hb & 0xffff0000u);
        ushort lo = (ushort)(__float_as_uint(h - hif) >> 16);
        int nl = w * 16 + nn;
        int u  = ((lane >> 3) ^ (nl & 7));
        int off = nl * 64 + u * 8 + (lane & 7);
        hhi[off] = hi;
        hlo[off] = lo;
    }
    __syncthreads();

    // phase 2: transposed MFMA -> vectorized stores
#pragma unroll
    for (int st = 0; st < 4; ++st) {
        int nloc = st * 16 + (lane & 15);
        short8 Ahi[2], Alo[2];
#pragma unroll
        for (int s = 0; s < 2; ++s) {
            int u = (s * 4 + (lane >> 4)) ^ (nloc & 7);
            int off = nloc * 64 + u * 8;
            Ahi[s] = *reinterpret_cast<const short8*>(hhi + off);
            Alo[s] = *reinterpret_cast<const short8*>(hlo + off);
        }
        int n = n0 + st * 16 + (lane & 15);
#pragma unroll
        for (int i = 0; i < 3; ++i) {
            int ct = w * 3 + i;
            f32x4 acc = {bias4[i].x, bias4[i].y, bias4[i].z, bias4[i].w};
#pragma unroll
            for (int s = 0; s < 2; ++s) {
                acc = __builtin_amdgcn_mfma_f32_16x16x32_bf16(Whi[i][s], Ahi[s], acc, 0, 0, 0);
                acc = __builtin_amdgcn_mfma_f32_16x16x32_bf16(Whi[i][s], Alo[s], acc, 0, 0, 0);
                acc = __builtin_amdgcn_mfma_f32_16x16x32_bf16(Wlo[i][s], Ahi[s], acc, 0, 0, 0);
                acc = __builtin_amdgcn_mfma_f32_16x16x32_bf16(Wlo[i][s], Alo[s], acc, 0, 0, 0);
            }
            if (n < N) {
                int chb = ct * 16 + (lane >> 4) * 4;
                if (chb < 64) {
                    uint2 pk;
                    pk.x = rne16(acc[0]) | (rne16(acc[1]) << 16);
                    pk.y = rne16(acc[2]) | (rne16(acc[3]) << 16);
                    *reinterpret_cast<uint2*>(zb + (size_t)n * HID + chb) = pk;
                } else if (chb < 128) {
                    float4 v = make_float4(acc[0], acc[1], acc[2], acc[3]);
                    *reinterpret_cast<float4*>(PQ + (size_t)n * HID + (chb - 64)) = v;
                } else {
                    uint2 pk;
                    pk.x = rne16(acc[0]) | (rne16(acc[1]) << 16);
                    pk.y = rne16(acc[2]) | (rne16(acc[3]) << 16);
                    *reinterpret_cast<uint2*>(Ppb + (size_t)n * HID + (chb - 128)) = pk;
                }
            }
        }
    }
}

// ---- exclusive scan (16/thread, 4096/block): raw chunk scans + chunk totals ----
__global__ void k_scan1(const int* __restrict__ cnt, int* __restrict__ rs,
                        int* __restrict__ bsum, int M) {
    __shared__ int lds[256];
    int t = threadIdx.x;
    int base = blockIdx.x * 4096 + t * 16;
    int v[16];
    if (base + 16 <= M) {
#pragma unroll
        for (int u = 0; u < 4; ++u) {
            int4 w = *reinterpret_cast<const int4*>(cnt + base + u * 4);
            v[u * 4 + 0] = w.x; v[u * 4 + 1] = w.y; v[u * 4 + 2] = w.z; v[u * 4 + 3] = w.w;
        }
    } else {
#pragma unroll
        for (int u = 0; u < 16; ++u) v[u] = (base + u < M) ? cnt[base + u] : 0;
    }
    int run = 0;
#pragma unroll
    for (int u = 0; u < 16; ++u) { int tv = v[u]; v[u] = run; run += tv; }
    lds[t] = run;
    __syncthreads();
#pragma unroll
    for (int off = 1; off < 256; off <<= 1) {
        int xw = (t >= off) ? lds[t - off] : 0;
        __syncthreads();
        lds[t] += xw;
        __syncthreads();
    }
    int excl = lds[t] - run;
    if (t == 255) bsum[blockIdx.x] = lds[255];
#pragma unroll
    for (int u = 0; u < 16; ++u)
        if (base + u < M) rs[base + u] = excl + v[u];
}

// ---- radix pass 1b: scatter packed (src | (dst&63)<<26) via LDS cursors ----
__global__ __launch_bounds__(256) void k_p1scat(const int* __restrict__ ei, const int* __restrict__ off,
                                                const int* __restrict__ bsum, int NBs,
                                                unsigned* __restrict__ tmp, int E, int B1) {
    __shared__ int cur[2048];
    __shared__ int lds[256];
    __shared__ int excl[256];
    int NB1 = gridDim.x;
    int t = threadIdx.x;
    int v = (t < NBs) ? bsum[t] : 0;
    lds[t] = v;
    __syncthreads();
#pragma unroll
    for (int o = 1; o < 256; o <<= 1) {
        int xw = (t >= o) ? lds[t - o] : 0;
        __syncthreads();
        lds[t] += xw;
        __syncthreads();
    }
    excl[t] = lds[t] - v;
    __syncthreads();
    for (int i = t; i < B1; i += 256) {
        int idx = i * NB1 + blockIdx.x;
        cur[i] = off[idx] + excl[idx >> 12];
    }
    __syncthreads();
    int CH = (E + NB1 - 1) / NB1;
    int e0 = blockIdx.x * CH;
    int e1 = min(e0 + CH, E);
    for (int e = e0 + t; e < e1; e += 256) {
        int s = ei[e];
        int d = ei[E + e];
        int pos = atomicAdd(&cur[d >> 6], 1);
        tmp[pos] = (unsigned)s | ((unsigned)(d & 63) << 26);
    }
}

// ---- fused radix pass 2 + gather + epilogue: one block per 64-node bucket ----
__global__ __launch_bounds__(256) void k_p2f(
    const unsigned* __restrict__ tmp, const int* __restrict__ off,
    const int* __restrict__ bsum, int NBs,
    const ushort* __restrict__ zb, const float* __restrict__ PQ, const ushort* __restrict__ Ppb,
    int* __restrict__ gcsr,
    const float* __restrict__ W2, const float* __restrict__ b2,
    float* __restrict__ out, int E, int N, int B1, int NB1)
{
    __shared__ int sc[256];
    __shared__ int h2[BKT];
    __shared__ int rsl[BKT];
    __shared__ int cur[BKT];
    __shared__ int bb[2];
    __shared__ int lcsr[LCAP];

    int b = blockIdx.x;
    int t = threadIdx.x;

    // bsum exscan -> bucket bounds
    {
        int v = (t < NBs) ? bsum[t] : 0;
        sc[t] = v;
        __syncthreads();
#pragma unroll
        for (int o = 1; o < 256; o <<= 1) {
            int xw = (t >= o) ? sc[t - o] : 0;
            __syncthreads();
            sc[t] += xw;
            __syncthreads();
        }
        if (t == 0) {
            int i0 = b * NB1;
            int c = i0 >> 12;
            bb[0] = off[i0] + (sc[c] - ((c < NBs) ? bsum[c] : 0));
        }
        if (t == 1) {
            if (b < B1 - 1) {
                int i1 = (b + 1) * NB1;
                int c = i1 >> 12;
                bb[1] = off[i1] + (sc[c] - ((c < NBs) ? bsum[c] : 0));
            } else bb[1] = E;
        }
        if (t < BKT) h2[t] = 0;
    }
    __syncthreads();
    int bb0 = bb[0], bb1 = bb[1];
    bool useg = (bb1 - bb0) > LCAP;

    // bin histogram (dst & 63)
    for (int i = bb0 + t; i < bb1; i += 256)
        atomicAdd(&h2[tmp[i] >> 26], 1);
    __syncthreads();

    // scan h2 (64 bins)
    int vdeg = (t < BKT) ? h2[t] : 0;
    sc[t] = vdeg;
    __syncthreads();
#pragma unroll
    for (int o = 1; o < BKT; o <<= 1) {
        int xw = (t >= o && t < BKT) ? sc[t - o] : 0;
        __syncthreads();
        if (t < BKT) sc[t] += xw;
        __syncthreads();
    }
    if (t < BKT) {
        int excl = sc[t] - vdeg;
        rsl[t] = excl;
        cur[t] = excl;
    }
    __syncthreads();

    // scatter src into local csr (global fallback if oversized bucket)
    if (!useg) {
        for (int i = bb0 + t; i < bb1; i += 256) {
            unsigned ed = tmp[i];
            int pos = atomicAdd(&cur[ed >> 26], 1);
            lcsr[pos] = (int)(ed & 0x03FFFFFFu);
        }
    } else {
        for (int i = bb0 + t; i < bb1; i += 256) {
            unsigned ed = tmp[i];
            int pos = atomicAdd(&cur[ed >> 26], 1);
            gcsr[bb0 + pos] = (int)(ed & 0x03FFFFFFu);
        }
    }
    __syncthreads();

    // gather + epilogue: 4 waves x 4 groups; 4 sweeps cover 64 nodes
    int lane = t & 63;
    int w    = t >> 6;
    int g    = lane >> 4;
    int ql   = lane & 15;
    int oct  = ql & 7;
    int half = ql >> 3;
    int c0 = oct * 8 + half * 4;
    float4 w2v = *reinterpret_cast<const float4*>(W2 + c0);
    float b2s = b2[0];

#pragma unroll
    for (int it = 0; it < BKT / 16; ++it) {
        int nl = it * 16 + w * 4 + g;
        int ng = b * BKT + nl;
        bool okg = ng < N;
        int beg = rsl[nl];
        int deg = h2[nl];
        int md = deg;
        md = max(md, __shfl_xor(md, 16));
        md = max(md, __shfl_xor(md, 32));

        float acc[8];
#pragma unroll
        for (int i = 0; i < 8; ++i) acc[i] = 0.f;

        for (int c = 0; c < md; c += 32) {
            int j0 = c + ql, j1 = c + 16 + ql;
            int ia = (j0 < deg) ? (useg ? gcsr[bb0 + beg + j0] : lcsr[beg + j0]) : -1;
            int ib = (j1 < deg) ? (useg ? gcsr[bb0 + beg + j1] : lcsr[beg + j1]) : -1;
#pragma unroll
            for (int tb = 0; tb < 4; ++tb) {
                if (tb > 0 && md <= c + 8 * tb) break;
                int srcs[4];
#pragma unroll
                for (int t4 = 0; t4 < 4; ++t4) {
                    int tt = tb * 4 + t4;
                    int e = 2 * tt + half;
                    srcs[t4] = __shfl(tb < 2 ? ia : ib, g * 16 + (e & 15));
                }
                uint4 rw[4];
#pragma unroll
                for (int t4 = 0; t4 < 4; ++t4) {
                    int s = srcs[t4] < 0 ? 0 : srcs[t4];
                    rw[t4] = *reinterpret_cast<const uint4*>(zb + (size_t)s * HID + oct * 8);
                }
#pragma unroll
                for (int t4 = 0; t4 < 4; ++t4) {
                    if (srcs[t4] >= 0) {
                        uint4 wv = rw[t4];
                        acc[0] += bitsf(wv.x << 16); acc[1] += bitsf(wv.x & 0xffff0000u);
                        acc[2] += bitsf(wv.y << 16); acc[3] += bitsf(wv.y & 0xffff0000u);
                        acc[4] += bitsf(wv.z << 16); acc[5] += bitsf(wv.z & 0xffff0000u);
                        acc[6] += bitsf(wv.w << 16); acc[7] += bitsf(wv.w & 0xffff0000u);
                    }
                }
            }
        }
#pragma unroll
        for (int i = 0; i < 8; ++i) acc[i] += __shfl_xor(acc[i], 8);

        float s0 = half ? acc[4] : acc[0];
        float s1 = half ? acc[5] : acc[1];
        float s2 = half ? acc[6] : acc[2];
        float s3 = half ? acc[7] : acc[3];

        float4 base = make_float4(0.f, 0.f, 0.f, 0.f);
        if (okg) {
            base = *reinterpret_cast<const float4*>(PQ + (size_t)ng * HID + c0);
            if (deg == 0) {
                uint2 pb = *reinterpret_cast<const uint2*>(Ppb + (size_t)ng * HID + c0);
                base.x = bitsf(pb.x << 16); base.y = bitsf(pb.x & 0xffff0000u);
                base.z = bitsf(pb.y << 16); base.w = bitsf(pb.y & 0xffff0000u);
            }
        }
        float rcpd = (deg > 0) ? (1.f / (float)deg) : 0.f;
        float y0 = base.x + s0 * rcpd;
        float y1 = base.y + s1 * rcpd;
        float y2 = base.z + s2 * rcpd;
        float y3 = base.w + s3 * rcpd;

        float part = fmaxf(y0, 0.f) * w2v.x + fmaxf(y1, 0.f) * w2v.y +
                     fmaxf(y2, 0.f) * w2v.z + fmaxf(y3, 0.f) * w2v.w;
#pragma unroll
        for (int off2 = 1; off2 < 16; off2 <<= 1) part += __shfl_xor(part, off2);
        if (ql == 0 && okg) out[ng] = part + b2s;
    }
}

extern "C" void kernel_launch(void* const* d_in, const int* in_sizes, int n_in,
                              void* d_out, int out_size, void* d_ws, size_t ws_size,
                              hipStream_t stream) {
    const float* x   = (const float*)d_in[0];
    const int*   ei  = (const int*)d_in[1];
    const float* W0  = (const float*)d_in[2];
    const float* b0  = (const float*)d_in[3];
    const float* W1  = (const float*)d_in[4];
    const float* b1  = (const float*)d_in[5];
    const float* W2  = (const float*)d_in[6];
    const float* b2  = (const float*)d_in[7];
    const float* M0  = (const float*)d_in[8];
    const float* bM0 = (const float*)d_in[9];

    int N = in_sizes[0] / IN_C;
    int E = in_sizes[1] / 2;
    int B1 = (N + BKT - 1) >> 6;        // 64-node buckets (<=2048 for N<=131072)
    int NB1 = 256;                      // pass-1 blocks
    int M2 = B1 * NB1;
    int NBs = (M2 + 4095) / 4096;       // scan chunks (<=256)

    ushort*   zb     = (ushort*)d_ws;                   // N*64 bf16
    float*    PQ     = (float*)(zb + (size_t)N * HID);  // N*64 f32
    ushort*   Ppb    = (ushort*)(PQ + (size_t)N * HID); // N*64 bf16
    ushort*   WPhi   = Ppb + (size_t)N * HID;           // 12288
    ushort*   WPlo   = WPhi + 12288;                    // 12288
    float*    bias192= (float*)(WPlo + 12288);          // 192
    int*      bhT    = (int*)(bias192 + 192);           // M2
    int*      off    = bhT + (size_t)M2;                // M2
    int*      bsum   = off + (size_t)M2;                // 256
    unsigned* tmp    = (unsigned*)(bsum + 256);         // E (packed)
    int*      gcsr   = (int*)(tmp + (size_t)E);         // E (fallback only)
    float*    out    = (float*)d_out;

    int npre = (N + 63) / 64;

    k_init<<<48, 256, 0, stream>>>(M0, W1, bM0, b1, WPhi, WPlo, bias192);
    k_pre_hist<<<NB1 + npre, 256, 0, stream>>>(x, W0, b0, WPhi, WPlo, bias192,
                                               zb, PQ, Ppb, N, ei, bhT, E, B1, NB1);
    k_scan1<<<NBs, 256, 0, stream>>>(bhT, off, bsum, M2);
    k_p1scat<<<NB1, 256, 0, stream>>>(ei, off, bsum, NBs, tmp, E, B1);
    k_p2f<<<B1, 256, 0, stream>>>(tmp, off, bsum, NBs, zb, PQ, Ppb, gcsr,
                                  W2, b2, out, E, N, B1, NB1);
}